// Round 10
// baseline (307.806 us; speedup 1.0000x reference)
//
#include <hip/hip_runtime.h>
#include <stdint.h>

#define T_TOK 4096
#define D_DIM 1024
#define F_DIM 4096
#define NEXP 8
#define BM 128
#define BN 128
#define BK 32
#define CAP 10240     // 8192 pairs + 8*255 worst-case padding, 256-aligned
#define MT256 (CAP / 256)   // 40
#define MT128 (CAP / 128)   // 80

typedef __attribute__((ext_vector_type(8))) short short8;
typedef __attribute__((ext_vector_type(4))) float f4;
typedef __attribute__((ext_vector_type(4))) unsigned short us4;

// ---- ws layout (bytes): round-3 proven footprint (172.1 MB, Y overlays xg) ----
#define WS_SBASE   64
#define WS_TBASE   96                                   // tbase256[9]
#define WS_TB128   160                                  // tbase128[9]
#define WS_TOPI    256
#define WS_TOPP    (WS_TOPI + T_TOK*2*4)
#define WS_PSLOT   (WS_TOPP + T_TOK*2*4)
#define WS_XG      102400                               // bf16 [CAP][D]; reused as Y
#define WS_H       (WS_XG + (size_t)CAP*D_DIM*2)        // bf16 [CAP][F]
#define WS_WT      (WS_H + (size_t)CAP*F_DIM*2)         // bf16 [E][N][K] (67 MB, reused)

__device__ __forceinline__ unsigned short f2bf(float f) {
    union { float f; uint32_t u; } c; c.f = f;
    uint32_t r = c.u + 0x7FFFu + ((c.u >> 16) & 1u);
    return (unsigned short)(r >> 16);
}
__device__ __forceinline__ float bf2f(unsigned short h) {
    union { uint32_t u; float f; } c; c.u = ((uint32_t)h) << 16;
    return c.f;
}

// ---------------- gate: fp32 logits, top-2, softmax (NO atomics) ----------------
__global__ __launch_bounds__(256) void gate_kernel(
    const float* __restrict__ x, const float* __restrict__ gw,
    const float* __restrict__ gb,
    int* __restrict__ top_idx, float* __restrict__ top_p)
{
    int lane = threadIdx.x & 63;
    int t = blockIdx.x * 4 + (threadIdx.x >> 6);
    const float* xr = x + (size_t)t * D_DIM;
    float acc[8] = {0.f,0.f,0.f,0.f,0.f,0.f,0.f,0.f};
    for (int i = 0; i < 16; ++i) {
        int d = lane + i * 64;
        float xv = xr[d];
        const float* g = gw + d * 8;
        #pragma unroll
        for (int e = 0; e < 8; ++e) acc[e] += xv * g[e];
    }
    #pragma unroll
    for (int e = 0; e < 8; ++e) {
        #pragma unroll
        for (int off = 32; off > 0; off >>= 1)
            acc[e] += __shfl_xor(acc[e], off, 64);
    }
    if (lane == 0) {
        float l[8];
        #pragma unroll
        for (int e = 0; e < 8; ++e) l[e] = acc[e] + gb[e];
        int i0 = 0; float m0 = l[0];
        #pragma unroll
        for (int e = 1; e < 8; ++e) if (l[e] > m0) { m0 = l[e]; i0 = e; }
        int i1 = -1; float m1 = -3.4e38f;
        #pragma unroll
        for (int e = 0; e < 8; ++e) if (e != i0 && l[e] > m1) { m1 = l[e]; i1 = e; }
        float p0 = 1.f / (1.f + expf(m1 - m0));
        top_idx[t*2]   = i0; top_idx[t*2+1] = i1;
        top_p[t*2]     = p0; top_p[t*2+1]   = 1.f - p0;
    }
}

// -------- plan: counts + 256-aligned bases + dual tile tables + rank slots --------
__global__ __launch_bounds__(256) void plan_kernel(
    const int* __restrict__ top_idx, int* __restrict__ sbase,
    int* __restrict__ tbase256, int* __restrict__ tbase128,
    int* __restrict__ pslot)
{
    __shared__ int woff[4][8];
    __shared__ int sb_s[8];
    int t = threadIdx.x, wv = t >> 6, lane = t & 63;
    int base = t * 32;

    int h[8] = {0,0,0,0,0,0,0,0};
    for (int i = 0; i < 32; ++i) {
        int e = top_idx[base + i];
        #pragma unroll
        for (int ee = 0; ee < 8; ++ee) h[ee] += (e == ee) ? 1 : 0;
    }
    int inc[8];
    #pragma unroll
    for (int ee = 0; ee < 8; ++ee) {
        int v = h[ee];
        #pragma unroll
        for (int off = 1; off < 64; off <<= 1) {
            int n = __shfl_up(v, off, 64);
            if (lane >= off) v += n;
        }
        inc[ee] = v;
    }
    if (lane == 63) {
        #pragma unroll
        for (int ee = 0; ee < 8; ++ee) woff[wv][ee] = inc[ee];
    }
    __syncthreads();
    if (t == 0) {
        int cnt[8];
        #pragma unroll
        for (int ee = 0; ee < 8; ++ee) {
            int s = 0;
            #pragma unroll
            for (int w = 0; w < 4; ++w) { int v = woff[w][ee]; woff[w][ee] = s; s += v; }
            cnt[ee] = s;
        }
        int b = 0, t2 = 0, t1 = 0;
        tbase256[0] = 0; tbase128[0] = 0;
        #pragma unroll
        for (int e = 0; e < 8; ++e) {
            sb_s[e] = b; sbase[e] = b;
            int m2 = (cnt[e] + 255) / 256;     // 256-row tiles (GEMM1)
            b  += m2 * 256;
            t2 += m2;
            t1 += m2 * 2;                      // same region as 128-row tiles (GEMM2)
            tbase256[e + 1] = t2;
            tbase128[e + 1] = t1;
        }
    }
    __syncthreads();
    int run[8];
    #pragma unroll
    for (int ee = 0; ee < 8; ++ee)
        run[ee] = sb_s[ee] + woff[wv][ee] + inc[ee] - h[ee];   // exclusive prefix
    for (int i = 0; i < 32; ++i) {
        int e = top_idx[base + i];
        int slot = 0;
        #pragma unroll
        for (int ee = 0; ee < 8; ++ee) slot += (e == ee) ? run[ee] : 0;
        pslot[base + i] = slot;
        #pragma unroll
        for (int ee = 0; ee < 8; ++ee) run[ee] += (e == ee) ? 1 : 0;
    }
}

// ---------------- gather: one block per TOKEN ----------------
__global__ __launch_bounds__(256) void gather_kernel(
    const float* __restrict__ x, const int* __restrict__ pslot,
    uint16_t* __restrict__ xg)
{
    int t = blockIdx.x;
    int s0 = pslot[2*t], s1 = pslot[2*t + 1];
    int i = threadIdx.x;
    f4 v = ((const f4*)(x + (size_t)t * D_DIM))[i];
    us4 o;
    o.x = f2bf(v[0]); o.y = f2bf(v[1]); o.z = f2bf(v[2]); o.w = f2bf(v[3]);
    *(us4*)(xg + (size_t)s0 * D_DIM + i * 4) = o;
    *(us4*)(xg + (size_t)s1 * D_DIM + i * 4) = o;
}

// ---- weight convert+transpose: fp32 [E][K][N] -> bf16 [E][N][K], 64x64 tiles ----
__global__ __launch_bounds__(512) void convT_kernel(
    const float* __restrict__ W, uint16_t* __restrict__ WT, int K, int N)
{
    __shared__ float ts[64][65];
    int e = blockIdx.z;
    int n0 = blockIdx.x * 64, k0 = blockIdx.y * 64;
    const float* src = W + (size_t)e * K * N + (size_t)k0 * N + n0;
    int t = threadIdx.x;
    int kk = t >> 3, j = t & 7;
    f4 v0 = *(const f4*)(src + (size_t)kk * N + j * 8);
    f4 v1 = *(const f4*)(src + (size_t)kk * N + j * 8 + 4);
    #pragma unroll
    for (int i = 0; i < 4; ++i) ts[j*8 + i][kk] = v0[i];
    #pragma unroll
    for (int i = 0; i < 4; ++i) ts[j*8 + 4 + i][kk] = v1[i];
    __syncthreads();
    int nn = t >> 3;
    short8 o;
    #pragma unroll
    for (int i = 0; i < 8; ++i) o[i] = (short)f2bf(ts[nn][j*8 + i]);
    *(short8*)(WT + (size_t)e * N * K + (size_t)(n0 + nn) * K + k0 + j * 8) = o;
}

// ------- grouped GEMM (PROVEN rounds 5/6): 128x128, ring-3, counted vmcnt -------
// All loop VMEM is global_load_lds (no global->VGPR loads) — immune to the
// compiler-waitcnt miscount that killed moe_gemm4.
template<bool RELU>
__global__ __launch_bounds__(256, 3) void moe_gemm3(
    const uint16_t* __restrict__ A, const uint16_t* __restrict__ Bt,
    const float* __restrict__ bias, uint16_t* __restrict__ Cc,
    const int* __restrict__ tbase, const int* __restrict__ sbase,
    int K, int N, int NT)
{
    __shared__ uint16_t As3[3][BM][BK];
    __shared__ uint16_t Bs3[3][BN][BK];

    int nwg = gridDim.x;
    int lin = blockIdx.x;
    int wg = (lin & 7) * (nwg >> 3) + (lin >> 3);
    int q = wg >> 2;
    int nt = q % NT;
    int mt = (wg & 3) + (q / NT) * 4;

    if (mt >= tbase[8]) return;
    int e = 0;
    while (mt >= tbase[e + 1]) ++e;
    int row0 = sbase[e] + (mt - tbase[e]) * BM;
    int n0 = nt * BN;
    const uint16_t* Be = Bt + (size_t)e * N * K + (size_t)n0 * K;

    int tid = threadIdx.x;
    int wid = tid >> 6, lane = tid & 63;
    int wrow = (wid >> 1) * 64, wcol = (wid & 1) * 64;

    f4 acc[4][4] = {};

    int ovb = tid * 16;
    int rowA[2], koffA[2];
    #pragma unroll
    for (int j = 0; j < 2; ++j) {
        int ov = ovb + j * 4096;
        int row = ov >> 6;
        int cb  = (ov >> 4) & 3;
        rowA[j]  = row;
        koffA[j] = (cb ^ ((row >> 1) & 3)) << 3;
    }

    int abyte[4], bbyte[4];
    #pragma unroll
    for (int m = 0; m < 4; ++m) {
        int r = wrow + m * 16 + (lane & 15);
        abyte[m] = r * 64 + ((((lane >> 4) ^ ((r >> 1) & 3))) << 4);
    }
    #pragma unroll
    for (int n = 0; n < 4; ++n) {
        int c = wcol + n * 16 + (lane & 15);
        bbyte[n] = c * 64 + ((((lane >> 4) ^ ((c >> 1) & 3))) << 4);
    }
    const char* As0 = (const char*)&As3[0][0][0];
    const char* Bs0 = (const char*)&Bs3[0][0][0];

    auto STAGE = [&](int buf, int kt) {   // 4 global_load_lds
        #pragma unroll
        for (int j = 0; j < 2; ++j) {
            const uint16_t* gpA = A + (size_t)(row0 + rowA[j]) * K + kt + koffA[j];
            __builtin_amdgcn_global_load_lds(
                (const __attribute__((address_space(1))) void*)gpA,
                (__attribute__((address_space(3))) void*)((char*)&As3[buf][0][0] + ovb + j * 4096),
                16, 0, 0);
            const uint16_t* gpB = Be + (size_t)rowA[j] * K + kt + koffA[j];
            __builtin_amdgcn_global_load_lds(
                (const __attribute__((address_space(1))) void*)gpB,
                (__attribute__((address_space(3))) void*)((char*)&Bs3[buf][0][0] + ovb + j * 4096),
                16, 0, 0);
        }
    };

    int nkt = K / BK;
    STAGE(0, 0);
    STAGE(1, BK);
    asm volatile("s_waitcnt vmcnt(4)" ::: "memory");
    __builtin_amdgcn_s_barrier();

    int buf = 0;
    for (int t = 0; t < nkt; ++t) {
        int cb = buf * 8192;
        short8 af[4], bfr[4];
        #pragma unroll
        for (int m = 0; m < 4; ++m) af[m] = *(const short8*)(As0 + cb + abyte[m]);
        #pragma unroll
        for (int n = 0; n < 4; ++n) bfr[n] = *(const short8*)(Bs0 + cb + bbyte[n]);

        bool stg = (t + 2) < nkt;
        if (stg) {
            int b2 = buf + 2; if (b2 >= 3) b2 -= 3;
            STAGE(b2, (t + 2) * BK);
        }

        #pragma unroll
        for (int m = 0; m < 4; ++m)
            #pragma unroll
            for (int n = 0; n < 4; ++n)
                acc[m][n] = __builtin_amdgcn_mfma_f32_16x16x32_bf16(
                    af[m], bfr[n], acc[m][n], 0, 0, 0);

        if (stg) asm volatile("s_waitcnt vmcnt(4)" ::: "memory");
        else     asm volatile("s_waitcnt vmcnt(0)" ::: "memory");
        __builtin_amdgcn_s_barrier();
        buf = (buf + 1 == 3) ? 0 : buf + 1;
    }

    #pragma unroll
    for (int n = 0; n < 4; ++n) {
        int c = wcol + n * 16 + (lane & 15);
        float bv = bias[(size_t)e * N + n0 + c];
        #pragma unroll
        for (int m = 0; m < 4; ++m) {
            int rb = wrow + m * 16 + (lane >> 4) * 4;
            #pragma unroll
            for (int r = 0; r < 4; ++r) {
                float v = acc[m][n][r] + bv;
                if (RELU) v = fmaxf(v, 0.f);
                Cc[(size_t)(row0 + rb + r) * N + n0 + c] = f2bf(v);
            }
        }
    }
}

// ------- grouped GEMM, 256x128 tile (parameter variant of the proven template) -------
// 4 waves each 128x64 out (acc 8x4) -> 12 ds_read_b128 per 32 MFMA (vs 8 per 16).
// Same ring-3 / separate-wait / swizzle formulas; STAGE = 6 global_load_lds
// (4 A-shots + 2 B-shots) -> waits (6,0). Loop VMEM is global_load_lds only.
template<bool RELU>
__global__ __launch_bounds__(256, 2) void moe_gemm5(
    const uint16_t* __restrict__ A, const uint16_t* __restrict__ Bt,
    const float* __restrict__ bias, uint16_t* __restrict__ Cc,
    const int* __restrict__ tbase, const int* __restrict__ sbase,
    int K, int N, int NT)
{
    __shared__ uint16_t As3[3][256][BK];   // 3 x 16 KB
    __shared__ uint16_t Bs3[3][BN][BK];    // 3 x 8 KB

    int nwg = gridDim.x;
    int lin = blockIdx.x;
    int wg = (lin & 7) * (nwg >> 3) + (lin >> 3);
    int q = wg >> 2;
    int nt = q % NT;
    int mt = (wg & 3) + (q / NT) * 4;

    if (mt >= tbase[8]) return;
    int e = 0;
    while (mt >= tbase[e + 1]) ++e;
    int row0 = sbase[e] + (mt - tbase[e]) * 256;
    int n0 = nt * BN;
    const uint16_t* Be = Bt + (size_t)e * N * K + (size_t)n0 * K;

    int tid = threadIdx.x;
    int wid = tid >> 6, lane = tid & 63;
    int wr = wid >> 1, wc = wid & 1;           // 2M x 2N waves
    int lq = lane >> 4, lr = lane & 15;

    f4 acc[8][4] = {};

    int ovb = tid * 16;
    // A: 4 shots cover 256 rows; B: 2 shots cover 128 rows (same formulas)
    int rowS[4], koffS[4];
    #pragma unroll
    for (int j = 0; j < 4; ++j) {
        int ov = ovb + j * 4096;
        int row = ov >> 6;
        int cb  = (ov >> 4) & 3;
        rowS[j]  = row;
        koffS[j] = (cb ^ ((row >> 1) & 3)) << 3;
    }

    int abyte[8], bbyte[4];
    #pragma unroll
    for (int m = 0; m < 8; ++m) {
        int r = wr * 128 + m * 16 + lr;
        abyte[m] = r * 64 + (((lq ^ ((r >> 1) & 3))) << 4);
    }
    #pragma unroll
    for (int n = 0; n < 4; ++n) {
        int c = wc * 64 + n * 16 + lr;
        bbyte[n] = c * 64 + (((lq ^ ((c >> 1) & 3))) << 4);
    }
    const char* As0 = (const char*)&As3[0][0][0];
    const char* Bs0 = (const char*)&Bs3[0][0][0];

    auto STAGE = [&](int buf, int kt) {   // 6 global_load_lds
        #pragma unroll
        for (int j = 0; j < 4; ++j) {
            const uint16_t* gpA = A + (size_t)(row0 + rowS[j]) * K + kt + koffS[j];
            __builtin_amdgcn_global_load_lds(
                (const __attribute__((address_space(1))) void*)gpA,
                (__attribute__((address_space(3))) void*)((char*)&As3[buf][0][0] + ovb + j * 4096),
                16, 0, 0);
        }
        #pragma unroll
        for (int j = 0; j < 2; ++j) {
            const uint16_t* gpB = Be + (size_t)rowS[j] * K + kt + koffS[j];
            __builtin_amdgcn_global_load_lds(
                (const __attribute__((address_space(1))) void*)gpB,
                (__attribute__((address_space(3))) void*)((char*)&Bs3[buf][0][0] + ovb + j * 4096),
                16, 0, 0);
        }
    };

    int nkt = K / BK;
    STAGE(0, 0);
    STAGE(1, BK);
    asm volatile("s_waitcnt vmcnt(6)" ::: "memory");
    __builtin_amdgcn_s_barrier();

    int buf = 0;
    for (int t = 0; t < nkt; ++t) {
        int cba = buf * 16384, cbb = buf * 8192;
        short8 af[8], bfr[4];
        #pragma unroll
        for (int m = 0; m < 8; ++m) af[m] = *(const short8*)(As0 + cba + abyte[m]);
        #pragma unroll
        for (int n = 0; n < 4; ++n) bfr[n] = *(const short8*)(Bs0 + cbb + bbyte[n]);

        bool stg = (t + 2) < nkt;
        if (stg) {
            int b2 = buf + 2; if (b2 >= 3) b2 -= 3;
            STAGE(b2, (t + 2) * BK);
        }

        #pragma unroll
        for (int m = 0; m < 8; ++m)
            #pragma unroll
            for (int n = 0; n < 4; ++n)
                acc[m][n] = __builtin_amdgcn_mfma_f32_16x16x32_bf16(
                    af[m], bfr[n], acc[m][n], 0, 0, 0);

        if (stg) asm volatile("s_waitcnt vmcnt(6)" ::: "memory");
        else     asm volatile("s_waitcnt vmcnt(0)" ::: "memory");
        __builtin_amdgcn_s_barrier();
        buf = (buf + 1 == 3) ? 0 : buf + 1;
    }

    #pragma unroll
    for (int n = 0; n < 4; ++n) {
        int c = wc * 64 + n * 16 + lr;
        float bv = bias[(size_t)e * N + n0 + c];
        #pragma unroll
        for (int m = 0; m < 8; ++m) {
            int rb = wr * 128 + m * 16 + lq * 4;
            #pragma unroll
            for (int r = 0; r < 4; ++r) {
                float v = acc[m][n][r] + bv;
                if (RELU) v = fmaxf(v, 0.f);
                Cc[(size_t)(row0 + rb + r) * N + n0 + c] = f2bf(v);
            }
        }
    }
}

// ---------------- combine ----------------
__global__ __launch_bounds__(256) void combine_kernel(
    const uint16_t* __restrict__ Y, const int* __restrict__ pair_slot,
    const float* __restrict__ top_p, float* __restrict__ out)
{
    int t = blockIdx.x;
    int s0 = pair_slot[t*2], s1 = pair_slot[t*2+1];
    float p0 = top_p[t*2],  p1 = top_p[t*2+1];
    int i = threadIdx.x * 4;
    us4 a = *(const us4*)(Y + (size_t)s0 * D_DIM + i);
    us4 b = *(const us4*)(Y + (size_t)s1 * D_DIM + i);
    f4 o;
    o[0] = p0 * bf2f(a.x) + p1 * bf2f(b.x);
    o[1] = p0 * bf2f(a.y) + p1 * bf2f(b.y);
    o[2] = p0 * bf2f(a.z) + p1 * bf2f(b.z);
    o[3] = p0 * bf2f(a.w) + p1 * bf2f(b.w);
    *(f4*)(out + (size_t)t * D_DIM + i) = o;
}

extern "C" void kernel_launch(void* const* d_in, const int* in_sizes, int n_in,
                              void* d_out, int out_size, void* d_ws, size_t ws_size,
                              hipStream_t stream)
{
    const float* x  = (const float*)d_in[0];
    const float* gw = (const float*)d_in[1];
    const float* gb = (const float*)d_in[2];
    const float* w1 = (const float*)d_in[3];
    const float* b1 = (const float*)d_in[4];
    const float* w2 = (const float*)d_in[5];
    const float* b2 = (const float*)d_in[6];
    float* out = (float*)d_out;

    char* ws = (char*)d_ws;
    int*   sbase = (int*)(ws + WS_SBASE);
    int*   tb256 = (int*)(ws + WS_TBASE);
    int*   tb128 = (int*)(ws + WS_TB128);
    int*   topi  = (int*)(ws + WS_TOPI);
    float* topp  = (float*)(ws + WS_TOPP);
    int*   pslot = (int*)(ws + WS_PSLOT);
    uint16_t* xg = (uint16_t*)(ws + WS_XG);
    uint16_t* H  = (uint16_t*)(ws + WS_H);
    uint16_t* Y  = xg;                       // xg dead after GEMM1 -> reuse as Y
    uint16_t* WT = (uint16_t*)(ws + WS_WT);

    gate_kernel<<<T_TOK / 4, 256, 0, stream>>>(x, gw, gb, topi, topp);
    plan_kernel<<<1, 256, 0, stream>>>(topi, sbase, tb256, tb128, pslot);
    gather_kernel<<<T_TOK, 256, 0, stream>>>(x, pslot, xg);

    convT_kernel<<<dim3(F_DIM/64, D_DIM/64, NEXP), 512, 0, stream>>>(w1, WT, D_DIM, F_DIM);
    moe_gemm5<true ><<<MT256 * (F_DIM / BN), 256, 0, stream>>>(
        xg, WT, b1, H, tb256, sbase, D_DIM, F_DIM, F_DIM / BN);
    convT_kernel<<<dim3(D_DIM/64, F_DIM/64, NEXP), 512, 0, stream>>>(w2, WT, F_DIM, D_DIM);
    moe_gemm3<false><<<MT128 * (D_DIM / BN), 256, 0, stream>>>(
        H, WT, b2, Y, tb128, sbase, F_DIM, D_DIM, D_DIM / BN);

    combine_kernel<<<T_TOK, 256, 0, stream>>>(Y, pslot, topp, out);
}

// Round 11
// 296.353 us; speedup vs baseline: 1.0386x; 1.0386x over previous
//
#include <hip/hip_runtime.h>
#include <stdint.h>

#define T_TOK 4096
#define D_DIM 1024
#define F_DIM 4096
#define NEXP 8
#define BM 128
#define BN 128
#define BN2 256
#define BK 32
#define CAP 9216      // 8192 pairs + 8*127 worst-case padding, 128-aligned
#define MT_MAX (CAP / BM)

typedef __attribute__((ext_vector_type(8))) short short8;
typedef __attribute__((ext_vector_type(4))) float f4;
typedef __attribute__((ext_vector_type(4))) unsigned short us4;

// ---- ws layout (bytes) — round-6 proven ----
#define WS_SBASE   64
#define WS_TBASE   96
#define WS_TOPI    256
#define WS_TOPP    (WS_TOPI + T_TOK*2*4)
#define WS_PSLOT   (WS_TOPP + T_TOK*2*4)
#define WS_XG      102400                               // bf16 [CAP][D]
#define WS_H       (WS_XG + (size_t)CAP*D_DIM*2)        // bf16 [CAP][F]
#define WS_Y       (WS_H + (size_t)CAP*F_DIM*2)         // bf16 [CAP][D]
#define WS_WT      (WS_Y + (size_t)CAP*D_DIM*2)         // bf16 [E][N][K] (67 MB, reused)

__device__ __forceinline__ unsigned short f2bf(float f) {
    union { float f; uint32_t u; } c; c.f = f;
    uint32_t r = c.u + 0x7FFFu + ((c.u >> 16) & 1u);
    return (unsigned short)(r >> 16);
}
__device__ __forceinline__ float bf2f(unsigned short h) {
    union { uint32_t u; float f; } c; c.u = ((uint32_t)h) << 16;
    return c.f;
}

// ---------------- gate: fp32 logits, top-2, softmax (NO atomics) ----------------
__global__ __launch_bounds__(256) void gate_kernel(
    const float* __restrict__ x, const float* __restrict__ gw,
    const float* __restrict__ gb,
    int* __restrict__ top_idx, float* __restrict__ top_p)
{
    int lane = threadIdx.x & 63;
    int t = blockIdx.x * 4 + (threadIdx.x >> 6);
    const float* xr = x + (size_t)t * D_DIM;
    float acc[8] = {0.f,0.f,0.f,0.f,0.f,0.f,0.f,0.f};
    for (int i = 0; i < 16; ++i) {
        int d = lane + i * 64;
        float xv = xr[d];
        const float* g = gw + d * 8;
        #pragma unroll
        for (int e = 0; e < 8; ++e) acc[e] += xv * g[e];
    }
    #pragma unroll
    for (int e = 0; e < 8; ++e) {
        #pragma unroll
        for (int off = 32; off > 0; off >>= 1)
            acc[e] += __shfl_xor(acc[e], off, 64);
    }
    if (lane == 0) {
        float l[8];
        #pragma unroll
        for (int e = 0; e < 8; ++e) l[e] = acc[e] + gb[e];
        int i0 = 0; float m0 = l[0];
        #pragma unroll
        for (int e = 1; e < 8; ++e) if (l[e] > m0) { m0 = l[e]; i0 = e; }
        int i1 = -1; float m1 = -3.4e38f;
        #pragma unroll
        for (int e = 0; e < 8; ++e) if (e != i0 && l[e] > m1) { m1 = l[e]; i1 = e; }
        float p0 = 1.f / (1.f + expf(m1 - m0));
        top_idx[t*2]   = i0; top_idx[t*2+1] = i1;
        top_p[t*2]     = p0; top_p[t*2+1]   = 1.f - p0;
    }
}

// ---------------- plan: counts + bases + deterministic rank-based slots ----------------
__global__ __launch_bounds__(256) void plan_kernel(
    const int* __restrict__ top_idx, int* __restrict__ sbase,
    int* __restrict__ tbase, int* __restrict__ pslot)
{
    __shared__ int woff[4][8];
    __shared__ int sb_s[8];
    int t = threadIdx.x, wv = t >> 6, lane = t & 63;
    int base = t * 32;

    int h[8] = {0,0,0,0,0,0,0,0};
    for (int i = 0; i < 32; ++i) {
        int e = top_idx[base + i];
        #pragma unroll
        for (int ee = 0; ee < 8; ++ee) h[ee] += (e == ee) ? 1 : 0;
    }
    int inc[8];
    #pragma unroll
    for (int ee = 0; ee < 8; ++ee) {
        int v = h[ee];
        #pragma unroll
        for (int off = 1; off < 64; off <<= 1) {
            int n = __shfl_up(v, off, 64);
            if (lane >= off) v += n;
        }
        inc[ee] = v;
    }
    if (lane == 63) {
        #pragma unroll
        for (int ee = 0; ee < 8; ++ee) woff[wv][ee] = inc[ee];
    }
    __syncthreads();
    if (t == 0) {
        int cnt[8];
        #pragma unroll
        for (int ee = 0; ee < 8; ++ee) {
            int s = 0;
            #pragma unroll
            for (int w = 0; w < 4; ++w) { int v = woff[w][ee]; woff[w][ee] = s; s += v; }
            cnt[ee] = s;
        }
        int b = 0, tb0 = 0;
        tbase[0] = 0;
        #pragma unroll
        for (int e = 0; e < 8; ++e) {
            sb_s[e] = b; sbase[e] = b;
            int mt = (cnt[e] + BM - 1) / BM;
            b += mt * BM; tb0 += mt;
            tbase[e + 1] = tb0;
        }
    }
    __syncthreads();
    int run[8];
    #pragma unroll
    for (int ee = 0; ee < 8; ++ee)
        run[ee] = sb_s[ee] + woff[wv][ee] + inc[ee] - h[ee];   // exclusive prefix
    for (int i = 0; i < 32; ++i) {
        int e = top_idx[base + i];
        int slot = 0;
        #pragma unroll
        for (int ee = 0; ee < 8; ++ee) slot += (e == ee) ? run[ee] : 0;
        pslot[base + i] = slot;
        #pragma unroll
        for (int ee = 0; ee < 8; ++ee) run[ee] += (e == ee) ? 1 : 0;
    }
}

// ---------------- gather: one block per TOKEN ----------------
__global__ __launch_bounds__(256) void gather_kernel(
    const float* __restrict__ x, const int* __restrict__ pslot,
    uint16_t* __restrict__ xg)
{
    int t = blockIdx.x;
    int s0 = pslot[2*t], s1 = pslot[2*t + 1];
    int i = threadIdx.x;
    f4 v = ((const f4*)(x + (size_t)t * D_DIM))[i];
    us4 o;
    o.x = f2bf(v[0]); o.y = f2bf(v[1]); o.z = f2bf(v[2]); o.w = f2bf(v[3]);
    *(us4*)(xg + (size_t)s0 * D_DIM + i * 4) = o;
    *(us4*)(xg + (size_t)s1 * D_DIM + i * 4) = o;
}

// ---- weight convert+transpose: fp32 [E][K][N] -> bf16 [E][N][K], 64x64 tiles ----
__global__ __launch_bounds__(512) void convT_kernel(
    const float* __restrict__ W, uint16_t* __restrict__ WT, int K, int N)
{
    __shared__ float ts[64][65];
    int e = blockIdx.z;
    int n0 = blockIdx.x * 64, k0 = blockIdx.y * 64;
    const float* src = W + (size_t)e * K * N + (size_t)k0 * N + n0;
    int t = threadIdx.x;
    int kk = t >> 3, j = t & 7;
    f4 v0 = *(const f4*)(src + (size_t)kk * N + j * 8);
    f4 v1 = *(const f4*)(src + (size_t)kk * N + j * 8 + 4);
    #pragma unroll
    for (int i = 0; i < 4; ++i) ts[j*8 + i][kk] = v0[i];
    #pragma unroll
    for (int i = 0; i < 4; ++i) ts[j*8 + 4 + i][kk] = v1[i];
    __syncthreads();
    int nn = t >> 3;
    short8 o;
    #pragma unroll
    for (int i = 0; i < 8; ++i) o[i] = (short)f2bf(ts[nn][j*8 + i]);
    *(short8*)(WT + (size_t)e * N * K + (size_t)(n0 + nn) * K + k0 + j * 8) = o;
}

// ------- grouped GEMM (PROVEN rounds 5/6): 128x128, 4 waves, ring-3, counted vmcnt -------
template<bool RELU>
__global__ __launch_bounds__(256, 3) void moe_gemm3(
    const uint16_t* __restrict__ A, const uint16_t* __restrict__ Bt,
    const float* __restrict__ bias, uint16_t* __restrict__ Cc,
    const int* __restrict__ tbase, const int* __restrict__ sbase,
    int K, int N, int NT)
{
    __shared__ uint16_t As3[3][BM][BK];
    __shared__ uint16_t Bs3[3][BN][BK];

    int nwg = gridDim.x;
    int lin = blockIdx.x;
    int wg = (lin & 7) * (nwg >> 3) + (lin >> 3);
    int q = wg >> 2;
    int nt = q % NT;
    int mt = (wg & 3) + (q / NT) * 4;

    if (mt >= tbase[8]) return;
    int e = 0;
    while (mt >= tbase[e + 1]) ++e;
    int row0 = sbase[e] + (mt - tbase[e]) * BM;
    int n0 = nt * BN;
    const uint16_t* Be = Bt + (size_t)e * N * K + (size_t)n0 * K;

    int tid = threadIdx.x;
    int wid = tid >> 6, lane = tid & 63;
    int wrow = (wid >> 1) * 64, wcol = (wid & 1) * 64;

    f4 acc[4][4] = {};

    int ovb = tid * 16;
    int rowA[2], koffA[2];
    #pragma unroll
    for (int j = 0; j < 2; ++j) {
        int ov = ovb + j * 4096;
        int row = ov >> 6;
        int cb  = (ov >> 4) & 3;
        rowA[j]  = row;
        koffA[j] = (cb ^ ((row >> 1) & 3)) << 3;
    }

    int abyte[4], bbyte[4];
    #pragma unroll
    for (int m = 0; m < 4; ++m) {
        int r = wrow + m * 16 + (lane & 15);
        abyte[m] = r * 64 + ((((lane >> 4) ^ ((r >> 1) & 3))) << 4);
    }
    #pragma unroll
    for (int n = 0; n < 4; ++n) {
        int c = wcol + n * 16 + (lane & 15);
        bbyte[n] = c * 64 + ((((lane >> 4) ^ ((c >> 1) & 3))) << 4);
    }
    const char* As0 = (const char*)&As3[0][0][0];
    const char* Bs0 = (const char*)&Bs3[0][0][0];

    auto STAGE = [&](int buf, int kt) {   // 4 global_load_lds
        #pragma unroll
        for (int j = 0; j < 2; ++j) {
            const uint16_t* gpA = A + (size_t)(row0 + rowA[j]) * K + kt + koffA[j];
            __builtin_amdgcn_global_load_lds(
                (const __attribute__((address_space(1))) void*)gpA,
                (__attribute__((address_space(3))) void*)((char*)&As3[buf][0][0] + ovb + j * 4096),
                16, 0, 0);
            const uint16_t* gpB = Be + (size_t)rowA[j] * K + kt + koffA[j];
            __builtin_amdgcn_global_load_lds(
                (const __attribute__((address_space(1))) void*)gpB,
                (__attribute__((address_space(3))) void*)((char*)&Bs3[buf][0][0] + ovb + j * 4096),
                16, 0, 0);
        }
    };

    int nkt = K / BK;
    STAGE(0, 0);
    STAGE(1, BK);
    asm volatile("s_waitcnt vmcnt(4)" ::: "memory");
    __builtin_amdgcn_s_barrier();

    int buf = 0;
    for (int t = 0; t < nkt; ++t) {
        int cb = buf * 8192;
        short8 af[4], bfr[4];
        #pragma unroll
        for (int m = 0; m < 4; ++m) af[m] = *(const short8*)(As0 + cb + abyte[m]);
        #pragma unroll
        for (int n = 0; n < 4; ++n) bfr[n] = *(const short8*)(Bs0 + cb + bbyte[n]);

        bool stg = (t + 2) < nkt;
        if (stg) {
            int b2 = buf + 2; if (b2 >= 3) b2 -= 3;
            STAGE(b2, (t + 2) * BK);
        }

        #pragma unroll
        for (int m = 0; m < 4; ++m)
            #pragma unroll
            for (int n = 0; n < 4; ++n)
                acc[m][n] = __builtin_amdgcn_mfma_f32_16x16x32_bf16(
                    af[m], bfr[n], acc[m][n], 0, 0, 0);

        if (stg) asm volatile("s_waitcnt vmcnt(4)" ::: "memory");
        else     asm volatile("s_waitcnt vmcnt(0)" ::: "memory");
        __builtin_amdgcn_s_barrier();
        buf = (buf + 1 == 3) ? 0 : buf + 1;
    }

    #pragma unroll
    for (int n = 0; n < 4; ++n) {
        int c = wcol + n * 16 + (lane & 15);
        float bv = bias[(size_t)e * N + n0 + c];
        #pragma unroll
        for (int m = 0; m < 4; ++m) {
            int rb = wrow + m * 16 + (lane >> 4) * 4;
            #pragma unroll
            for (int r = 0; r < 4; ++r) {
                float v = acc[m][n][r] + bv;
                if (RELU) v = fmaxf(v, 0.f);
                Cc[(size_t)(row0 + rb + r) * N + n0 + c] = f2bf(v);
            }
        }
    }
}

// ------- grouped GEMM, 128x256 tile, 512 thr / 8 waves (2M x 4N, 64x64 each) -------
// Inner loop identical to the proven moe_gemm3 (8 ds_read_b128 + 16 MFMA per
// K-step per wave; same swizzle formulas). LDS 72 KB -> 2 blocks x 8 waves =
// 16 waves/CU (vs 12). STAGE = 3 global_load_lds (A 1 shot, B 2 shots) ->
// waits vmcnt(3)/vmcnt(0) by the proven derivation. Loop VMEM is
// global_load_lds ONLY (hand-vmcnt safety rule from round 9).
template<bool RELU>
__global__ __launch_bounds__(512, 4) void moe_gemm6(
    const uint16_t* __restrict__ A, const uint16_t* __restrict__ Bt,
    const float* __restrict__ bias, uint16_t* __restrict__ Cc,
    const int* __restrict__ tbase, const int* __restrict__ sbase,
    int K, int N, int NT)
{
    __shared__ uint16_t As3[3][BM][BK];    // 3 x 8 KB
    __shared__ uint16_t Bs3[3][BN2][BK];   // 3 x 16 KB

    int nwg = gridDim.x;
    int lin = blockIdx.x;
    int wg = (lin & 7) * (nwg >> 3) + (lin >> 3);
    int q = wg >> 2;
    int nt = q % NT;
    int mt = (wg & 3) + (q / NT) * 4;

    if (mt >= tbase[8]) return;
    int e = 0;
    while (mt >= tbase[e + 1]) ++e;
    int row0 = sbase[e] + (mt - tbase[e]) * BM;
    int n0 = nt * BN2;
    const uint16_t* Be = Bt + (size_t)e * N * K + (size_t)n0 * K;

    int tid = threadIdx.x;
    int wid = tid >> 6, lane = tid & 63;
    int wrow = (wid >> 2) * 64, wcol = (wid & 3) * 64;   // 2M x 4N waves
    int lq = lane >> 4, lr = lane & 15;

    f4 acc[4][4] = {};

    int ovb = tid * 16;                    // 512 thr x 16B = 8 KB per shot-range
    // A: 1 shot covers 128 rows; B: 2 shots cover 256 rows (same formulas)
    int rowS[2], koffS[2];
    #pragma unroll
    for (int j = 0; j < 2; ++j) {
        int ov = ovb + j * 8192;
        int row = ov >> 6;
        int cb  = (ov >> 4) & 3;
        rowS[j]  = row;
        koffS[j] = (cb ^ ((row >> 1) & 3)) << 3;
    }

    int abyte[4], bbyte[4];
    #pragma unroll
    for (int m = 0; m < 4; ++m) {
        int r = wrow + m * 16 + lr;
        abyte[m] = r * 64 + (((lq ^ ((r >> 1) & 3))) << 4);
    }
    #pragma unroll
    for (int n = 0; n < 4; ++n) {
        int c = wcol + n * 16 + lr;        // c in 0..255
        bbyte[n] = c * 64 + (((lq ^ ((c >> 1) & 3))) << 4);
    }
    const char* As0 = (const char*)&As3[0][0][0];
    const char* Bs0 = (const char*)&Bs3[0][0][0];

    auto STAGE = [&](int buf, int kt) {   // 3 global_load_lds per thread
        const uint16_t* gpA = A + (size_t)(row0 + rowS[0]) * K + kt + koffS[0];
        __builtin_amdgcn_global_load_lds(
            (const __attribute__((address_space(1))) void*)gpA,
            (__attribute__((address_space(3))) void*)((char*)&As3[buf][0][0] + ovb),
            16, 0, 0);
        #pragma unroll
        for (int j = 0; j < 2; ++j) {
            const uint16_t* gpB = Be + (size_t)rowS[j] * K + kt + koffS[j];
            __builtin_amdgcn_global_load_lds(
                (const __attribute__((address_space(1))) void*)gpB,
                (__attribute__((address_space(3))) void*)((char*)&Bs3[buf][0][0] + ovb + j * 8192),
                16, 0, 0);
        }
    };

    int nkt = K / BK;
    STAGE(0, 0);
    STAGE(1, BK);
    asm volatile("s_waitcnt vmcnt(3)" ::: "memory");
    __builtin_amdgcn_s_barrier();

    int buf = 0;
    for (int t = 0; t < nkt; ++t) {
        int cba = buf * 8192, cbb = buf * 16384;
        short8 af[4], bfr[4];
        #pragma unroll
        for (int m = 0; m < 4; ++m) af[m] = *(const short8*)(As0 + cba + abyte[m]);
        #pragma unroll
        for (int n = 0; n < 4; ++n) bfr[n] = *(const short8*)(Bs0 + cbb + bbyte[n]);

        bool stg = (t + 2) < nkt;
        if (stg) {
            int b2 = buf + 2; if (b2 >= 3) b2 -= 3;
            STAGE(b2, (t + 2) * BK);
        }

        #pragma unroll
        for (int m = 0; m < 4; ++m)
            #pragma unroll
            for (int n = 0; n < 4; ++n)
                acc[m][n] = __builtin_amdgcn_mfma_f32_16x16x32_bf16(
                    af[m], bfr[n], acc[m][n], 0, 0, 0);

        if (stg) asm volatile("s_waitcnt vmcnt(3)" ::: "memory");
        else     asm volatile("s_waitcnt vmcnt(0)" ::: "memory");
        __builtin_amdgcn_s_barrier();
        buf = (buf + 1 == 3) ? 0 : buf + 1;
    }

    #pragma unroll
    for (int n = 0; n < 4; ++n) {
        int c = wcol + n * 16 + lr;
        float bv = bias[(size_t)e * N + n0 + c];
        #pragma unroll
        for (int m = 0; m < 4; ++m) {
            int rb = wrow + m * 16 + lq * 4;
            #pragma unroll
            for (int r = 0; r < 4; ++r) {
                float v = acc[m][n][r] + bv;
                if (RELU) v = fmaxf(v, 0.f);
                Cc[(size_t)(row0 + rb + r) * N + n0 + c] = f2bf(v);
            }
        }
    }
}

// ---------------- combine ----------------
__global__ __launch_bounds__(256) void combine_kernel(
    const uint16_t* __restrict__ Y, const int* __restrict__ pair_slot,
    const float* __restrict__ top_p, float* __restrict__ out)
{
    int t = blockIdx.x;
    int s0 = pair_slot[t*2], s1 = pair_slot[t*2+1];
    float p0 = top_p[t*2],  p1 = top_p[t*2+1];
    int i = threadIdx.x * 4;
    us4 a = *(const us4*)(Y + (size_t)s0 * D_DIM + i);
    us4 b = *(const us4*)(Y + (size_t)s1 * D_DIM + i);
    f4 o;
    o[0] = p0 * bf2f(a.x) + p1 * bf2f(b.x);
    o[1] = p0 * bf2f(a.y) + p1 * bf2f(b.y);
    o[2] = p0 * bf2f(a.z) + p1 * bf2f(b.z);
    o[3] = p0 * bf2f(a.w) + p1 * bf2f(b.w);
    *(f4*)(out + (size_t)t * D_DIM + i) = o;
}

extern "C" void kernel_launch(void* const* d_in, const int* in_sizes, int n_in,
                              void* d_out, int out_size, void* d_ws, size_t ws_size,
                              hipStream_t stream)
{
    const float* x  = (const float*)d_in[0];
    const float* gw = (const float*)d_in[1];
    const float* gb = (const float*)d_in[2];
    const float* w1 = (const float*)d_in[3];
    const float* b1 = (const float*)d_in[4];
    const float* w2 = (const float*)d_in[5];
    const float* b2 = (const float*)d_in[6];
    float* out = (float*)d_out;

    char* ws = (char*)d_ws;
    int*   sbase = (int*)(ws + WS_SBASE);
    int*   tbase = (int*)(ws + WS_TBASE);
    int*   topi  = (int*)(ws + WS_TOPI);
    float* topp  = (float*)(ws + WS_TOPP);
    int*   pslot = (int*)(ws + WS_PSLOT);
    uint16_t* xg = (uint16_t*)(ws + WS_XG);
    uint16_t* H  = (uint16_t*)(ws + WS_H);
    uint16_t* Y  = (uint16_t*)(ws + WS_Y);
    uint16_t* WT = (uint16_t*)(ws + WS_WT);

    gate_kernel<<<T_TOK / 4, 256, 0, stream>>>(x, gw, gb, topi, topp);
    plan_kernel<<<1, 256, 0, stream>>>(topi, sbase, tbase, pslot);
    gather_kernel<<<T_TOK, 256, 0, stream>>>(x, pslot, xg);

    convT_kernel<<<dim3(F_DIM/64, D_DIM/64, NEXP), 512, 0, stream>>>(w1, WT, D_DIM, F_DIM);
    moe_gemm6<true ><<<MT_MAX * (F_DIM / BN2), 512, 0, stream>>>(
        xg, WT, b1, H, tbase, sbase, D_DIM, F_DIM, F_DIM / BN2);
    convT_kernel<<<dim3(D_DIM/64, F_DIM/64, NEXP), 512, 0, stream>>>(w2, WT, F_DIM, D_DIM);
    moe_gemm3<false><<<MT_MAX * (D_DIM / BN), 256, 0, stream>>>(
        H, WT, b2, Y, tbase, sbase, F_DIM, D_DIM, D_DIM / BN);

    combine_kernel<<<T_TOK, 256, 0, stream>>>(Y, pslot, topp, out);
}

// Round 12
// 288.334 us; speedup vs baseline: 1.0675x; 1.0278x over previous
//
#include <hip/hip_runtime.h>
#include <stdint.h>

#define T_TOK 4096
#define D_DIM 1024
#define F_DIM 4096
#define NEXP 8
#define BM 128
#define BN 128
#define BN2 256
#define BK 32
#define CAP 9216      // 8192 pairs + 8*127 worst-case padding, 128-aligned
#define MT_MAX (CAP / BM)

typedef __attribute__((ext_vector_type(8))) short short8;
typedef __attribute__((ext_vector_type(4))) float f4;
typedef __attribute__((ext_vector_type(4))) unsigned short us4;

// ---- ws layout (bytes) ----
#define WS_SBASE   64
#define WS_TBASE   96
#define WS_TOPI    256
#define WS_TOPP    (WS_TOPI + T_TOK*2*4)
#define WS_PSLOT   (WS_TOPP + T_TOK*2*4)
#define WS_XG      102400                               // bf16 [CAP][D]
#define WS_H       (WS_XG + (size_t)CAP*D_DIM*2)        // bf16 [CAP][F]
#define WS_Y       (WS_H + (size_t)CAP*F_DIM*2)         // bf16 [CAP][D]
#define WS_WT1     (WS_Y + (size_t)CAP*D_DIM*2)         // bf16 [E][F][D] (67 MB)
#define WT_BYTES   ((size_t)NEXP*D_DIM*F_DIM*2)
#define WS_WT2     (WS_WT1 + WT_BYTES)                  // bf16 [E][D][F] (fused path only)
#define WS_NEED_FUSED (WS_WT2 + WT_BYTES)               // 247,566,336 B

__device__ __forceinline__ unsigned short f2bf(float f) {
    union { float f; uint32_t u; } c; c.f = f;
    uint32_t r = c.u + 0x7FFFu + ((c.u >> 16) & 1u);
    return (unsigned short)(r >> 16);
}
__device__ __forceinline__ float bf2f(unsigned short h) {
    union { uint32_t u; float f; } c; c.u = ((uint32_t)h) << 16;
    return c.f;
}

// ---------------- gate: fp32 logits, top-2, softmax (NO atomics) ----------------
__global__ __launch_bounds__(256) void gate_kernel(
    const float* __restrict__ x, const float* __restrict__ gw,
    const float* __restrict__ gb,
    int* __restrict__ top_idx, float* __restrict__ top_p)
{
    int lane = threadIdx.x & 63;
    int t = blockIdx.x * 4 + (threadIdx.x >> 6);
    const float* xr = x + (size_t)t * D_DIM;
    float acc[8] = {0.f,0.f,0.f,0.f,0.f,0.f,0.f,0.f};
    for (int i = 0; i < 16; ++i) {
        int d = lane + i * 64;
        float xv = xr[d];
        const float* g = gw + d * 8;
        #pragma unroll
        for (int e = 0; e < 8; ++e) acc[e] += xv * g[e];
    }
    #pragma unroll
    for (int e = 0; e < 8; ++e) {
        #pragma unroll
        for (int off = 32; off > 0; off >>= 1)
            acc[e] += __shfl_xor(acc[e], off, 64);
    }
    if (lane == 0) {
        float l[8];
        #pragma unroll
        for (int e = 0; e < 8; ++e) l[e] = acc[e] + gb[e];
        int i0 = 0; float m0 = l[0];
        #pragma unroll
        for (int e = 1; e < 8; ++e) if (l[e] > m0) { m0 = l[e]; i0 = e; }
        int i1 = -1; float m1 = -3.4e38f;
        #pragma unroll
        for (int e = 0; e < 8; ++e) if (e != i0 && l[e] > m1) { m1 = l[e]; i1 = e; }
        float p0 = 1.f / (1.f + expf(m1 - m0));
        top_idx[t*2]   = i0; top_idx[t*2+1] = i1;
        top_p[t*2]     = p0; top_p[t*2+1]   = 1.f - p0;
    }
}

// ---------------- plan: counts + bases + deterministic rank-based slots ----------------
__global__ __launch_bounds__(256) void plan_kernel(
    const int* __restrict__ top_idx, int* __restrict__ sbase,
    int* __restrict__ tbase, int* __restrict__ pslot)
{
    __shared__ int woff[4][8];
    __shared__ int sb_s[8];
    int t = threadIdx.x, wv = t >> 6, lane = t & 63;
    int base = t * 32;

    int h[8] = {0,0,0,0,0,0,0,0};
    for (int i = 0; i < 32; ++i) {
        int e = top_idx[base + i];
        #pragma unroll
        for (int ee = 0; ee < 8; ++ee) h[ee] += (e == ee) ? 1 : 0;
    }
    int inc[8];
    #pragma unroll
    for (int ee = 0; ee < 8; ++ee) {
        int v = h[ee];
        #pragma unroll
        for (int off = 1; off < 64; off <<= 1) {
            int n = __shfl_up(v, off, 64);
            if (lane >= off) v += n;
        }
        inc[ee] = v;
    }
    if (lane == 63) {
        #pragma unroll
        for (int ee = 0; ee < 8; ++ee) woff[wv][ee] = inc[ee];
    }
    __syncthreads();
    if (t == 0) {
        int cnt[8];
        #pragma unroll
        for (int ee = 0; ee < 8; ++ee) {
            int s = 0;
            #pragma unroll
            for (int w = 0; w < 4; ++w) { int v = woff[w][ee]; woff[w][ee] = s; s += v; }
            cnt[ee] = s;
        }
        int b = 0, tb0 = 0;
        tbase[0] = 0;
        #pragma unroll
        for (int e = 0; e < 8; ++e) {
            sb_s[e] = b; sbase[e] = b;
            int mt = (cnt[e] + BM - 1) / BM;
            b += mt * BM; tb0 += mt;
            tbase[e + 1] = tb0;
        }
    }
    __syncthreads();
    int run[8];
    #pragma unroll
    for (int ee = 0; ee < 8; ++ee)
        run[ee] = sb_s[ee] + woff[wv][ee] + inc[ee] - h[ee];   // exclusive prefix
    for (int i = 0; i < 32; ++i) {
        int e = top_idx[base + i];
        int slot = 0;
        #pragma unroll
        for (int ee = 0; ee < 8; ++ee) slot += (e == ee) ? run[ee] : 0;
        pslot[base + i] = slot;
        #pragma unroll
        for (int ee = 0; ee < 8; ++ee) run[ee] += (e == ee) ? 1 : 0;
    }
}

// ---------------- gather: one block per TOKEN ----------------
__global__ __launch_bounds__(256) void gather_kernel(
    const float* __restrict__ x, const int* __restrict__ pslot,
    uint16_t* __restrict__ xg)
{
    int t = blockIdx.x;
    int s0 = pslot[2*t], s1 = pslot[2*t + 1];
    int i = threadIdx.x;
    f4 v = ((const f4*)(x + (size_t)t * D_DIM))[i];
    us4 o;
    o.x = f2bf(v[0]); o.y = f2bf(v[1]); o.z = f2bf(v[2]); o.w = f2bf(v[3]);
    *(us4*)(xg + (size_t)s0 * D_DIM + i * 4) = o;
    *(us4*)(xg + (size_t)s1 * D_DIM + i * 4) = o;
}

// ---- weight convert+transpose body: fp32 [E][K][N] -> bf16 [E][N][K], 64x64 tile ----
__device__ __forceinline__ void convT_body(
    char* smemraw, int nx, int ky, int e,
    const float* __restrict__ W, uint16_t* __restrict__ WT, int K, int N)
{
    float (*ts)[65] = (float(*)[65])smemraw;   // 64x65 fp32 = 16640 B
    int n0 = nx * 64, k0 = ky * 64;
    const float* src = W + (size_t)e * K * N + (size_t)k0 * N + n0;
    int t = threadIdx.x;
    int kk = t >> 3, j = t & 7;
    f4 v0 = *(const f4*)(src + (size_t)kk * N + j * 8);
    f4 v1 = *(const f4*)(src + (size_t)kk * N + j * 8 + 4);
    #pragma unroll
    for (int i = 0; i < 4; ++i) ts[j*8 + i][kk] = v0[i];
    #pragma unroll
    for (int i = 0; i < 4; ++i) ts[j*8 + 4 + i][kk] = v1[i];
    __syncthreads();
    int nn = t >> 3;
    short8 o;
    #pragma unroll
    for (int i = 0; i < 8; ++i) o[i] = (short)f2bf(ts[nn][j*8 + i]);
    *(short8*)(WT + (size_t)e * N * K + (size_t)(n0 + nn) * K + k0 + j * 8) = o;
}

__global__ __launch_bounds__(512) void convT_kernel(
    const float* __restrict__ W, uint16_t* __restrict__ WT, int K, int N)
{
    __shared__ __align__(16) char smem[16640];
    convT_body(smem, blockIdx.x, blockIdx.y, blockIdx.z, W, WT, K, N);
}

// ------- grouped GEMM body, 128x256 tile, 512 thr / 8 waves (round-11 proven) -------
// Inner loop = proven moe_gemm3 schedule (ring-3, counted vmcnt(3)/(0),
// global_load_lds-only VMEM). LDS 72 KB via caller-provided smem union.
template<bool RELU>
__device__ __forceinline__ void gemm6_body(
    char* smemraw, int lin, int nwg,
    const uint16_t* __restrict__ A, const uint16_t* __restrict__ Bt,
    const float* __restrict__ bias, uint16_t* __restrict__ Cc,
    const int* __restrict__ tbase, const int* __restrict__ sbase,
    int K, int N, int NT)
{
    char* As0c = smemraw;              // 3 x [128][32] bf16 = 24576 B
    char* Bs0c = smemraw + 24576;      // 3 x [256][32] bf16 = 49152 B

    int wg = (lin & 7) * (nwg >> 3) + (lin >> 3);
    int q = wg >> 2;
    int nt = q % NT;
    int mt = (wg & 3) + (q / NT) * 4;

    if (mt >= tbase[8]) return;
    int e = 0;
    while (mt >= tbase[e + 1]) ++e;
    int row0 = sbase[e] + (mt - tbase[e]) * BM;
    int n0 = nt * BN2;
    const uint16_t* Be = Bt + (size_t)e * N * K + (size_t)n0 * K;

    int tid = threadIdx.x;
    int wid = tid >> 6, lane = tid & 63;
    int wrow = (wid >> 2) * 64, wcol = (wid & 3) * 64;   // 2M x 4N waves
    int lq = lane >> 4, lr = lane & 15;

    f4 acc[4][4] = {};

    int ovb = tid * 16;                    // 512 thr x 16B = 8 KB per shot-range
    int rowS[2], koffS[2];
    #pragma unroll
    for (int j = 0; j < 2; ++j) {
        int ov = ovb + j * 8192;
        int row = ov >> 6;
        int cb  = (ov >> 4) & 3;
        rowS[j]  = row;
        koffS[j] = (cb ^ ((row >> 1) & 3)) << 3;
    }

    int abyte[4], bbyte[4];
    #pragma unroll
    for (int m = 0; m < 4; ++m) {
        int r = wrow + m * 16 + lr;
        abyte[m] = r * 64 + (((lq ^ ((r >> 1) & 3))) << 4);
    }
    #pragma unroll
    for (int n = 0; n < 4; ++n) {
        int c = wcol + n * 16 + lr;        // c in 0..255
        bbyte[n] = c * 64 + (((lq ^ ((c >> 1) & 3))) << 4);
    }

    auto STAGE = [&](int buf, int kt) {   // 3 global_load_lds per thread
        const uint16_t* gpA = A + (size_t)(row0 + rowS[0]) * K + kt + koffS[0];
        __builtin_amdgcn_global_load_lds(
            (const __attribute__((address_space(1))) void*)gpA,
            (__attribute__((address_space(3))) void*)(As0c + buf * 8192 + ovb),
            16, 0, 0);
        #pragma unroll
        for (int j = 0; j < 2; ++j) {
            const uint16_t* gpB = Be + (size_t)rowS[j] * K + kt + koffS[j];
            __builtin_amdgcn_global_load_lds(
                (const __attribute__((address_space(1))) void*)gpB,
                (__attribute__((address_space(3))) void*)(Bs0c + buf * 16384 + ovb + j * 8192),
                16, 0, 0);
        }
    };

    int nkt = K / BK;
    STAGE(0, 0);
    STAGE(1, BK);
    asm volatile("s_waitcnt vmcnt(3)" ::: "memory");
    __builtin_amdgcn_s_barrier();

    int buf = 0;
    for (int t = 0; t < nkt; ++t) {
        int cba = buf * 8192, cbb = buf * 16384;
        short8 af[4], bfr[4];
        #pragma unroll
        for (int m = 0; m < 4; ++m) af[m] = *(const short8*)(As0c + cba + abyte[m]);
        #pragma unroll
        for (int n = 0; n < 4; ++n) bfr[n] = *(const short8*)(Bs0c + cbb + bbyte[n]);

        bool stg = (t + 2) < nkt;
        if (stg) {
            int b2 = buf + 2; if (b2 >= 3) b2 -= 3;
            STAGE(b2, (t + 2) * BK);
        }

        #pragma unroll
        for (int m = 0; m < 4; ++m)
            #pragma unroll
            for (int n = 0; n < 4; ++n)
                acc[m][n] = __builtin_amdgcn_mfma_f32_16x16x32_bf16(
                    af[m], bfr[n], acc[m][n], 0, 0, 0);

        if (stg) asm volatile("s_waitcnt vmcnt(3)" ::: "memory");
        else     asm volatile("s_waitcnt vmcnt(0)" ::: "memory");
        __builtin_amdgcn_s_barrier();
        buf = (buf + 1 == 3) ? 0 : buf + 1;
    }

    #pragma unroll
    for (int n = 0; n < 4; ++n) {
        int c = wcol + n * 16 + lr;
        float bv = bias[(size_t)e * N + n0 + c];
        #pragma unroll
        for (int m = 0; m < 4; ++m) {
            int rb = wrow + m * 16 + lq * 4;
            #pragma unroll
            for (int r = 0; r < 4; ++r) {
                float v = acc[m][n][r] + bv;
                if (RELU) v = fmaxf(v, 0.f);
                Cc[(size_t)(row0 + rb + r) * N + n0 + c] = f2bf(v);
            }
        }
    }
}

// standalone (fallback path)
template<bool RELU>
__global__ __launch_bounds__(512, 4) void moe_gemm6(
    const uint16_t* __restrict__ A, const uint16_t* __restrict__ Bt,
    const float* __restrict__ bias, uint16_t* __restrict__ Cc,
    const int* __restrict__ tbase, const int* __restrict__ sbase,
    int K, int N, int NT)
{
    __shared__ __align__(16) char smem[73728];
    gemm6_body<RELU>(smem, blockIdx.x, gridDim.x, A, Bt, bias, Cc,
                     tbase, sbase, K, N, NT);
}

// ---- fused: GEMM1 blocks [0,g1) + convT(w2) blocks [g1, g1+8192) ----
// One 72 KB smem union keeps GEMM occupancy at 2 blocks/CU; convT blocks fill
// CU slots as GEMM rounds retire, hiding w2 conversion under GEMM compute.
__global__ __launch_bounds__(512, 4) void gemm1_convw2_fused(
    const uint16_t* __restrict__ A, const uint16_t* __restrict__ Bt,
    const float* __restrict__ bias, uint16_t* __restrict__ Cc,
    const int* __restrict__ tbase, const int* __restrict__ sbase,
    int K, int N, int NT, int g1,
    const float* __restrict__ W2, uint16_t* __restrict__ WT2, int K2, int N2)
{
    __shared__ __align__(16) char smem[73728];
    int bid = blockIdx.x;
    if (bid < g1) {
        gemm6_body<true>(smem, bid, g1, A, Bt, bias, Cc, tbase, sbase, K, N, NT);
    } else {
        int b2 = bid - g1;                 // [0, 8*64*16)
        int e  = b2 >> 10;                 // /1024
        int rem = b2 & 1023;
        int ky = rem >> 4;                 // /16
        int nx = rem & 15;
        convT_body(smem, nx, ky, e, W2, WT2, K2, N2);
    }
}

// ------- grouped GEMM (PROVEN rounds 5/6): 128x128, 4 waves, ring-3, counted vmcnt -------
template<bool RELU>
__global__ __launch_bounds__(256, 3) void moe_gemm3(
    const uint16_t* __restrict__ A, const uint16_t* __restrict__ Bt,
    const float* __restrict__ bias, uint16_t* __restrict__ Cc,
    const int* __restrict__ tbase, const int* __restrict__ sbase,
    int K, int N, int NT)
{
    __shared__ uint16_t As3[3][BM][BK];
    __shared__ uint16_t Bs3[3][BN][BK];

    int nwg = gridDim.x;
    int lin = blockIdx.x;
    int wg = (lin & 7) * (nwg >> 3) + (lin >> 3);
    int q = wg >> 2;
    int nt = q % NT;
    int mt = (wg & 3) + (q / NT) * 4;

    if (mt >= tbase[8]) return;
    int e = 0;
    while (mt >= tbase[e + 1]) ++e;
    int row0 = sbase[e] + (mt - tbase[e]) * BM;
    int n0 = nt * BN;
    const uint16_t* Be = Bt + (size_t)e * N * K + (size_t)n0 * K;

    int tid = threadIdx.x;
    int wid = tid >> 6, lane = tid & 63;
    int wrow = (wid >> 1) * 64, wcol = (wid & 1) * 64;

    f4 acc[4][4] = {};

    int ovb = tid * 16;
    int rowA[2], koffA[2];
    #pragma unroll
    for (int j = 0; j < 2; ++j) {
        int ov = ovb + j * 4096;
        int row = ov >> 6;
        int cb  = (ov >> 4) & 3;
        rowA[j]  = row;
        koffA[j] = (cb ^ ((row >> 1) & 3)) << 3;
    }

    int abyte[4], bbyte[4];
    #pragma unroll
    for (int m = 0; m < 4; ++m) {
        int r = wrow + m * 16 + (lane & 15);
        abyte[m] = r * 64 + ((((lane >> 4) ^ ((r >> 1) & 3))) << 4);
    }
    #pragma unroll
    for (int n = 0; n < 4; ++n) {
        int c = wcol + n * 16 + (lane & 15);
        bbyte[n] = c * 64 + ((((lane >> 4) ^ ((c >> 1) & 3))) << 4);
    }
    const char* As0 = (const char*)&As3[0][0][0];
    const char* Bs0 = (const char*)&Bs3[0][0][0];

    auto STAGE = [&](int buf, int kt) {   // 4 global_load_lds
        #pragma unroll
        for (int j = 0; j < 2; ++j) {
            const uint16_t* gpA = A + (size_t)(row0 + rowA[j]) * K + kt + koffA[j];
            __builtin_amdgcn_global_load_lds(
                (const __attribute__((address_space(1))) void*)gpA,
                (__attribute__((address_space(3))) void*)((char*)&As3[buf][0][0] + ovb + j * 4096),
                16, 0, 0);
            const uint16_t* gpB = Be + (size_t)rowA[j] * K + kt + koffA[j];
            __builtin_amdgcn_global_load_lds(
                (const __attribute__((address_space(1))) void*)gpB,
                (__attribute__((address_space(3))) void*)((char*)&Bs3[buf][0][0] + ovb + j * 4096),
                16, 0, 0);
        }
    };

    int nkt = K / BK;
    STAGE(0, 0);
    STAGE(1, BK);
    asm volatile("s_waitcnt vmcnt(4)" ::: "memory");
    __builtin_amdgcn_s_barrier();

    int buf = 0;
    for (int t = 0; t < nkt; ++t) {
        int cb = buf * 8192;
        short8 af[4], bfr[4];
        #pragma unroll
        for (int m = 0; m < 4; ++m) af[m] = *(const short8*)(As0 + cb + abyte[m]);
        #pragma unroll
        for (int n = 0; n < 4; ++n) bfr[n] = *(const short8*)(Bs0 + cb + bbyte[n]);

        bool stg = (t + 2) < nkt;
        if (stg) {
            int b2 = buf + 2; if (b2 >= 3) b2 -= 3;
            STAGE(b2, (t + 2) * BK);
        }

        #pragma unroll
        for (int m = 0; m < 4; ++m)
            #pragma unroll
            for (int n = 0; n < 4; ++n)
                acc[m][n] = __builtin_amdgcn_mfma_f32_16x16x32_bf16(
                    af[m], bfr[n], acc[m][n], 0, 0, 0);

        if (stg) asm volatile("s_waitcnt vmcnt(4)" ::: "memory");
        else     asm volatile("s_waitcnt vmcnt(0)" ::: "memory");
        __builtin_amdgcn_s_barrier();
        buf = (buf + 1 == 3) ? 0 : buf + 1;
    }

    #pragma unroll
    for (int n = 0; n < 4; ++n) {
        int c = wcol + n * 16 + (lane & 15);
        float bv = bias[(size_t)e * N + n0 + c];
        #pragma unroll
        for (int m = 0; m < 4; ++m) {
            int rb = wrow + m * 16 + (lane >> 4) * 4;
            #pragma unroll
            for (int r = 0; r < 4; ++r) {
                float v = acc[m][n][r] + bv;
                if (RELU) v = fmaxf(v, 0.f);
                Cc[(size_t)(row0 + rb + r) * N + n0 + c] = f2bf(v);
            }
        }
    }
}

// ---------------- combine ----------------
__global__ __launch_bounds__(256) void combine_kernel(
    const uint16_t* __restrict__ Y, const int* __restrict__ pair_slot,
    const float* __restrict__ top_p, float* __restrict__ out)
{
    int t = blockIdx.x;
    int s0 = pair_slot[t*2], s1 = pair_slot[t*2+1];
    float p0 = top_p[t*2],  p1 = top_p[t*2+1];
    int i = threadIdx.x * 4;
    us4 a = *(const us4*)(Y + (size_t)s0 * D_DIM + i);
    us4 b = *(const us4*)(Y + (size_t)s1 * D_DIM + i);
    f4 o;
    o[0] = p0 * bf2f(a.x) + p1 * bf2f(b.x);
    o[1] = p0 * bf2f(a.y) + p1 * bf2f(b.y);
    o[2] = p0 * bf2f(a.z) + p1 * bf2f(b.z);
    o[3] = p0 * bf2f(a.w) + p1 * bf2f(b.w);
    *(f4*)(out + (size_t)t * D_DIM + i) = o;
}

extern "C" void kernel_launch(void* const* d_in, const int* in_sizes, int n_in,
                              void* d_out, int out_size, void* d_ws, size_t ws_size,
                              hipStream_t stream)
{
    const float* x  = (const float*)d_in[0];
    const float* gw = (const float*)d_in[1];
    const float* gb = (const float*)d_in[2];
    const float* w1 = (const float*)d_in[3];
    const float* b1 = (const float*)d_in[4];
    const float* w2 = (const float*)d_in[5];
    const float* b2 = (const float*)d_in[6];
    float* out = (float*)d_out;

    char* ws = (char*)d_ws;
    int*   sbase = (int*)(ws + WS_SBASE);
    int*   tbase = (int*)(ws + WS_TBASE);
    int*   topi  = (int*)(ws + WS_TOPI);
    float* topp  = (float*)(ws + WS_TOPP);
    int*   pslot = (int*)(ws + WS_PSLOT);
    uint16_t* xg  = (uint16_t*)(ws + WS_XG);
    uint16_t* H   = (uint16_t*)(ws + WS_H);
    uint16_t* Y   = (uint16_t*)(ws + WS_Y);
    uint16_t* WT1 = (uint16_t*)(ws + WS_WT1);
    uint16_t* WT2 = (uint16_t*)(ws + WS_WT2);

    gate_kernel<<<T_TOK / 4, 256, 0, stream>>>(x, gw, gb, topi, topp);
    plan_kernel<<<1, 256, 0, stream>>>(topi, sbase, tbase, pslot);
    gather_kernel<<<T_TOK, 256, 0, stream>>>(x, pslot, xg);

    convT_kernel<<<dim3(F_DIM/64, D_DIM/64, NEXP), 512, 0, stream>>>(w1, WT1, D_DIM, F_DIM);

    const int g1 = MT_MAX * (F_DIM / BN2);          // 72 * 16 = 1152
    if (ws_size >= WS_NEED_FUSED) {
        // fused: GEMM1 + convT(w2) in one grid; convT hides under GEMM compute
        const int cblk = NEXP * (F_DIM/64) * (D_DIM/64);   // 8192
        gemm1_convw2_fused<<<g1 + cblk, 512, 0, stream>>>(
            xg, WT1, b1, H, tbase, sbase, D_DIM, F_DIM, F_DIM / BN2, g1,
            w2, WT2, F_DIM, D_DIM);
        moe_gemm3<false><<<MT_MAX * (D_DIM / BN), 256, 0, stream>>>(
            H, WT2, b2, Y, tbase, sbase, F_DIM, D_DIM, D_DIM / BN);
    } else {
        // fallback = round-11 exact (single WT buffer, serial convT(w2))
        moe_gemm6<true><<<g1, 512, 0, stream>>>(
            xg, WT1, b1, H, tbase, sbase, D_DIM, F_DIM, F_DIM / BN2);
        convT_kernel<<<dim3(D_DIM/64, F_DIM/64, NEXP), 512, 0, stream>>>(w2, WT1, F_DIM, D_DIM);
        moe_gemm3<false><<<MT_MAX * (D_DIM / BN), 256, 0, stream>>>(
            H, WT1, b2, Y, tbase, sbase, F_DIM, D_DIM, D_DIM / BN);
    }

    combine_kernel<<<T_TOK, 256, 0, stream>>>(Y, pslot, topp, out);
}